// Round 7
// baseline (6514.190 us; speedup 1.0000x reference)
//
#include <hip/hip_runtime.h>

// LSTM: B=64, T=512, D=1024, H=1024.
// v4 changes vs v3 (6105 us; v3 regressed fused 5697->5876):
//   - REVERT h-load pipeline to v2's 8-deep rolling buffer (v3's ap[32]
//     never materialized: VGPR=152 proves scheduler serialized it; v2's
//     explicit rolling form measured 5697).
//   - ys stores REMOVED from the scan step. ys[b][t][:] == hbuf[t+1][b][:],
//     so a post-pass ys_copy kernel (f16->f32, ~35us at HBM BW) produces
//     them. Removes 4 HBM stores from every step's vmcnt tail (in-order
//     vmcnt forces the next poll's flag read to drain them at vmcnt(0)).
//   - keeps: gemm fusion, wave-class flags, first-flag-sample, xv dbuf.

typedef _Float16 half8 __attribute__((ext_vector_type(8)));
typedef float floatx4 __attribute__((ext_vector_type(4)));

__device__ __forceinline__ void gll16(const void* g, void* l) {
  __builtin_amdgcn_global_load_lds(
      (const __attribute__((address_space(1))) unsigned int*)g,
      (__attribute__((address_space(3))) unsigned int*)l, 16, 0, 0);
}

__device__ __forceinline__ float sigm(float x) { return 1.f / (1.f + __expf(-x)); }
__device__ __forceinline__ float tanhfast(float x) { return 1.f - 2.f / (__expf(2.f * x) + 1.f); }

// ---------------- prep: convert xs (t-major rows), h0; zero flags/cnt/tot ----------------
__global__ void prep_ew(const float* __restrict__ xs, const float* __restrict__ h0,
                        _Float16* __restrict__ xs16, _Float16* __restrict__ hb0,
                        int* __restrict__ flags) {
  long gid = (long)blockIdx.x * blockDim.x + threadIdx.x;
  if (gid < 4194304) {
    const float4* p = (const float4*)xs + gid * 2;
    float4 u = p[0], w = p[1];
    half8 o;
    o[0] = (_Float16)u.x; o[1] = (_Float16)u.y; o[2] = (_Float16)u.z; o[3] = (_Float16)u.w;
    o[4] = (_Float16)w.x; o[5] = (_Float16)w.y; o[6] = (_Float16)w.z; o[7] = (_Float16)w.w;
    long e = gid * 8;
    long row = e >> 10;               // b*512 + t
    long b = row >> 9, t = row & 511;
    *(half8*)(xs16 + ((t << 6) + b) * 1024 + (e & 1023)) = o;  // row t*64+b
  } else if (gid < 4202496) {
    long j = gid - 4194304;
    const float4* p = (const float4*)h0 + j * 2;
    float4 u = p[0], w = p[1];
    half8 o;
    o[0] = (_Float16)u.x; o[1] = (_Float16)u.y; o[2] = (_Float16)u.z; o[3] = (_Float16)u.w;
    o[4] = (_Float16)w.x; o[5] = (_Float16)w.y; o[6] = (_Float16)w.z; o[7] = (_Float16)w.w;
    *(half8*)(hb0 + j * 8) = o;
  } else if (gid < 4203264) {
    flags[gid - 4202496] = 0;  // flags[0..255], cnt[256..511], tot[512], pad
  }
}

// ---------------- transpose [1024][4096] f32 -> [4096][1024] f16 ----------------
__global__ void transpose_k(const float* __restrict__ in, _Float16* __restrict__ outp) {
  __shared__ float s[32][33];
  int bx = blockIdx.x * 32, by = blockIdx.y * 32;
  int tx = threadIdx.x, ty = threadIdx.y;
#pragma unroll
  for (int k = 0; k < 32; k += 8)
    s[ty + k][tx] = in[(long)(by + ty + k) * 4096 + bx + tx];
  __syncthreads();
#pragma unroll
  for (int k = 0; k < 32; k += 8)
    outp[(long)(bx + ty + k) * 1024 + by + tx] = (_Float16)s[tx][ty + k];
}

// ---------------- ys_copy: out.ys[b][t][h] = (f32)hbuf[t+1][b][h] ----------------
__global__ void ys_copy(const _Float16* __restrict__ hbuf, float* __restrict__ out) {
  long gid = (long)blockIdx.x * blockDim.x + threadIdx.x;  // 4194304 threads
  long e = 65536 + gid * 8;              // hbuf element index (t=1..512 frames)
  half8 hv = *(const half8*)(hbuf + e);
  long t1 = e >> 16;                     // 1..512
  long b = (e >> 10) & 63, h = e & 1023;
  float* o = out + 131072 + b * 524288 + (t1 - 1) * 1024 + h;
  float4 u, w;
  u.x = (float)hv[0]; u.y = (float)hv[1]; u.z = (float)hv[2]; u.w = (float)hv[3];
  w.x = (float)hv[4]; w.y = (float)hv[5]; w.z = (float)hv[6]; w.w = (float)hv[7];
  *(float4*)o = u;
  *(float4*)(o + 4) = w;
}

// ---------------- fused: gemm1 workers + persistent scan ----------------
__global__ __launch_bounds__(256, 1) void fused(const _Float16* __restrict__ xs16,
                                                const _Float16* __restrict__ wxt,
                                                _Float16* __restrict__ xprj,
                                                const _Float16* __restrict__ wht,
                                                const float* __restrict__ bias,
                                                const float* __restrict__ c0,
                                                _Float16* __restrict__ hbuf,
                                                int* __restrict__ flags,
                                                float* __restrict__ out) {
  __shared__ char smem[131072];
  const int tid = threadIdx.x;
  int* const cnt = flags + 256;
  int* const tot = flags + 512;

  if (blockIdx.x >= 64) {
    // ---------------- gemm1 tile ----------------
    _Float16* sA = (_Float16*)smem;
    _Float16* sB = (_Float16*)(smem + 8192);
    const int gid = blockIdx.x - 64;
    const int by = gid >> 5, bx = gid & 31;
    const int w = tid >> 6, l = tid & 63, li = l & 15, q = l >> 4;
    const int wr = w >> 1, wc = w & 1;
    const int m0 = by * 128, n0 = bx * 128;
    floatx4 acc[4][4] = {};
    const _Float16* gA0 = xs16 + (long)(m0 + (w * 16 + li)) * 1024 + q * 8;
    const _Float16* gA1 = xs16 + (long)(m0 + ((4 + w) * 16 + li)) * 1024 + q * 8;
    const _Float16* gB0 = wxt + (long)(n0 + (w * 16 + li)) * 1024 + q * 8;
    const _Float16* gB1 = wxt + (long)(n0 + ((4 + w) * 16 + li)) * 1024 + q * 8;
    _Float16* lA0 = sA + (w * 64) * 8;
    _Float16* lA1 = sA + (256 + w * 64) * 8;
    _Float16* lB0 = sB + (w * 64) * 8;
    _Float16* lB1 = sB + (256 + w * 64) * 8;
    for (int k0 = 0; k0 < 1024; k0 += 32) {
      __syncthreads();
      gll16(gA0 + k0, lA0);
      gll16(gA1 + k0, lA1);
      gll16(gB0 + k0, lB0);
      gll16(gB1 + k0, lB1);
      __syncthreads();
      half8 af[4], bf[4];
      const half8* pA = (const half8*)sA;
      const half8* pB = (const half8*)sB;
#pragma unroll
      for (int i = 0; i < 4; i++) af[i] = pA[(wr * 4 + i) * 64 + l];
#pragma unroll
      for (int j = 0; j < 4; j++) bf[j] = pB[(wc * 4 + j) * 64 + l];
#pragma unroll
      for (int i = 0; i < 4; i++)
#pragma unroll
        for (int j = 0; j < 4; j++)
          acc[i][j] = __builtin_amdgcn_mfma_f32_16x16x32_f16(af[i], bf[j], acc[i][j], 0, 0, 0);
    }
#pragma unroll
    for (int i = 0; i < 4; i++) {
#pragma unroll
      for (int r = 0; r < 4; r++) {
        int m = m0 + wr * 64 + i * 16 + q * 4 + r;  // row already t*64+b
#pragma unroll
        for (int j = 0; j < 4; j++) {
          int gn = n0 + wc * 64 + j * 16 + li;
          xprj[(long)m * 4096 + gn] = (_Float16)acc[i][j][r];
        }
      }
    }
    __syncthreads();  // drains all threads' C stores (vmcnt 0 before barrier)
    if (tid == 0) {
      __builtin_amdgcn_fence(__ATOMIC_RELEASE, "agent");
      __hip_atomic_fetch_add(&cnt[by], 1, __ATOMIC_RELAXED, __HIP_MEMORY_SCOPE_AGENT);
      __hip_atomic_fetch_add(tot, 1, __ATOMIC_RELAXED, __HIP_MEMORY_SCOPE_AGENT);
    }
    return;
  }

  // ---------------- scan ----------------
  _Float16* sW = (_Float16*)smem;  // [g(4)][kk(32)][lane(64)][8] = 128 KB
  const int wgid = blockIdx.x;     // 0..63
  const int v = tid >> 6;          // wave 0..3
  const int l = tid & 63, li = l & 15, q = l >> 4;
  const int ks = wgid * 16;

  // stage Wh^T slice into LDS once: 8192 x 16B chunks
#pragma unroll 4
  for (int i = 0; i < 32; i++) {
    int c = i * 256 + tid;
    int g = c >> 11, kk = (c >> 6) & 31;
    int cli = c & 15, cq = (c >> 4) & 3;
    gll16(wht + (long)((g << 10) + ks + cli) * 1024 + kk * 32 + cq * 8,
          sW + (long)(c - l) * 8);
  }
  float creg[4];
#pragma unroll
  for (int r = 0; r < 4; r++)
    creg[r] = c0[(long)(v * 16 + q * 4 + r) * 1024 + ks + li];
  float bs[4];
#pragma unroll
  for (int g = 0; g < 4; g++) bs[g] = bias[(g << 10) + ks + li];
  __syncthreads();  // sW resident; last barrier in the kernel

  const half8* pW = (const half8*)sW;
  const int fidx = 4 * l + v;  // lane l audits wg l, OWN wave-class only
  int xdone = 0;

  // prologue: gate group 0, prefetch xv[0] into xvA
  for (;;) {
    int cr = __hip_atomic_load(&cnt[0], __ATOMIC_RELAXED, __HIP_MEMORY_SCOPE_AGENT);
    if (cr >= 32) break;
    __builtin_amdgcn_s_sleep(16);
  }
  xdone = (__hip_atomic_load(tot, __ATOMIC_RELAXED, __HIP_MEMORY_SCOPE_AGENT) >= 8192);
  __builtin_amdgcn_fence(__ATOMIC_ACQUIRE, "agent");
  _Float16 xvA[4][4], xvB[4][4];
  {
    const _Float16* xp0 = xprj + ks + li;
#pragma unroll
    for (int g = 0; g < 4; g++)
#pragma unroll
      for (int r = 0; r < 4; r++)
        xvA[g][r] = xp0[(long)(v * 16 + q * 4 + r) * 4096 + (g << 10)];
  }

// STEP(T, XC, XN, DOGATE): run step T using xproj regs XC, prefetch T+1 into XN.
#define STEP(T, XC, XN, DOGATE)                                                           \
  {                                                                                       \
    const int t_ = (T);                                                                   \
    /* 1. first flag sample, issued before the xv prefetch loads */                       \
    int f_ = __hip_atomic_load(&flags[fidx], __ATOMIC_RELAXED, __HIP_MEMORY_SCOPE_AGENT); \
    /* 2. gate next xproj group (rarely active; only during gemm phase) */                \
    if (DOGATE && (t_ + 1) < 512 && !xdone) {                                             \
      const int nb_ = (t_ + 1) >> 1;                                                      \
      for (;;) {                                                                          \
        int cr_ = __hip_atomic_load(&cnt[nb_], __ATOMIC_RELAXED, __HIP_MEMORY_SCOPE_AGENT); \
        if (cr_ >= 32) break;                                                             \
        __builtin_amdgcn_s_sleep(16);                                                     \
      }                                                                                   \
      xdone = (__hip_atomic_load(tot, __ATOMIC_RELAXED, __HIP_MEMORY_SCOPE_AGENT) >= 8192); \
      __builtin_amdgcn_fence(__ATOMIC_ACQUIRE, "agent");                                  \
    }                                                                                     \
    /* 3. issue next step's xv prefetch (completes during K-loop) */                      \
    if ((t_ + 1) < 512) {                                                                 \
      const _Float16* xpn_ = xprj + (long)(t_ + 1) * 262144 + ks + li;                    \
      _Pragma("unroll") for (int g = 0; g < 4; g++)                                       \
        _Pragma("unroll") for (int r = 0; r < 4; r++)                                     \
          XN[g][r] = xpn_[(long)(v * 16 + q * 4 + r) * 4096 + (g << 10)];                 \
    }                                                                                     \
    /* 4. finish flag poll (first check only needs f_) */                                 \
    for (;;) {                                                                            \
      if (__all(f_ >= t_)) break;                                                         \
      __builtin_amdgcn_s_sleep(1);                                                        \
      f_ = __hip_atomic_load(&flags[fidx], __ATOMIC_RELAXED, __HIP_MEMORY_SCOPE_AGENT);   \
    }                                                                                     \
    __builtin_amdgcn_fence(__ATOMIC_ACQUIRE, "workgroup");                                \
    /* 5. K-loop: 8-deep rolling h pipeline (v2 form, measured-good) */                   \
    const _Float16* hrow_ = hbuf + (long)t_ * 65536 + (long)(v * 16 + li) * 1024 + q * 8; \
    floatx4 acc_[4] = {};                                                                 \
    half8 ap_[8];                                                                         \
    _Pragma("unroll") for (int p = 0; p < 8; p++)                                         \
      ap_[p] = *(const half8*)(hrow_ + p * 32);                                           \
    _Pragma("unroll") for (int kk = 0; kk < 32; kk++) {                                   \
      half8 a_ = ap_[kk & 7];                                                             \
      _Pragma("unroll") for (int g = 0; g < 4; g++)                                       \
        acc_[g] = __builtin_amdgcn_mfma_f32_16x16x32_f16(a_, pW[((g * 32 + kk) << 6) + l], acc_[g], 0, 0, 0); \
      if (kk < 24) ap_[kk & 7] = *(const half8*)(hrow_ + (kk + 8) * 32);                  \
    }                                                                                     \
    /* 6. lane-local gates, h store, publish */                                           \
    _Float16* hnext_ = hbuf + (long)(t_ + 1) * 65536;                                     \
    float hval_[4], cval_[4];                                                             \
    _Pragma("unroll") for (int r = 0; r < 4; r++) {                                       \
      float gi = acc_[0][r] + (float)XC[0][r] + bs[0];                                    \
      float gf = acc_[1][r] + (float)XC[1][r] + bs[1];                                    \
      float gg = acc_[2][r] + (float)XC[2][r] + bs[2];                                    \
      float go = acc_[3][r] + (float)XC[3][r] + bs[3];                                    \
      float cN = sigm(gf) * creg[r] + sigm(gi) * tanhfast(gg);                            \
      creg[r] = cN;                                                                       \
      cval_[r] = cN;                                                                      \
      float hN = sigm(go) * tanhfast(cN);                                                 \
      hval_[r] = hN;                                                                      \
      int b_ = v * 16 + q * 4 + r;                                                        \
      unsigned short hu_ = __builtin_bit_cast(unsigned short, (_Float16)hN);              \
      __hip_atomic_store((unsigned short*)hnext_ + (long)b_ * 1024 + ks + li, hu_,        \
                         __ATOMIC_RELAXED, __HIP_MEMORY_SCOPE_AGENT);                     \
    }                                                                                     \
    __builtin_amdgcn_s_waitcnt(0); /* drains ONLY the 4 h stores */                       \
    if (l == 0)                                                                           \
      __hip_atomic_store(&flags[4 * wgid + v], t_ + 1, __ATOMIC_RELAXED, __HIP_MEMORY_SCOPE_AGENT); \
    /* 7. final cT/hT only (ys produced by ys_copy post-pass) */                          \
    if (t_ == 511) {                                                                      \
      _Pragma("unroll") for (int r = 0; r < 4; r++) {                                     \
        int b_ = v * 16 + q * 4 + r;                                                      \
        out[(long)b_ * 1024 + ks + li] = cval_[r];                                        \
        out[65536 + (long)b_ * 1024 + ks + li] = hval_[r];                                \
      }                                                                                   \
    }                                                                                     \
  }

  for (int t2 = 0; t2 < 512; t2 += 2) {
    STEP(t2, xvA, xvB, 0)      // even t: next is odd, same xproj group
    STEP(t2 + 1, xvB, xvA, 1)  // odd t: next is even, gate new group
  }
#undef STEP
}

// ---------------- host ----------------
extern "C" void kernel_launch(void* const* d_in, const int* in_sizes, int n_in,
                              void* d_out, int out_size, void* d_ws, size_t ws_size,
                              hipStream_t stream) {
  const float* c0 = (const float*)d_in[0];
  const float* h0 = (const float*)d_in[1];
  const float* xs = (const float*)d_in[2];
  const float* Wx = (const float*)d_in[3];
  const float* Wh = (const float*)d_in[4];
  const float* bias = (const float*)d_in[5];
  float* out = (float*)d_out;

  char* ws = (char*)d_ws;
  size_t off = 0;
  _Float16* xs16 = (_Float16*)(ws + off); off += 67108864;    // 32768x1024 f16 (t-major rows)
  _Float16* wxt  = (_Float16*)(ws + off); off += 8388608;     // 4096x1024 f16
  _Float16* wht  = (_Float16*)(ws + off); off += 8388608;     // 4096x1024 f16
  _Float16* xprj = (_Float16*)(ws + off); off += 268435456;   // 32768x4096 f16
  _Float16* hbuf = (_Float16*)(ws + off); off += 67239936;    // 513x64x1024 f16
  int* flags     = (int*)(ws + off);      off += 4096;        // flags[256], cnt[256], tot
  if (ws_size < off) return;

  prep_ew<<<16419, 256, 0, stream>>>(xs, h0, xs16, hbuf, flags);
  transpose_k<<<dim3(128, 32), dim3(32, 8), 0, stream>>>(Wx, wxt);
  transpose_k<<<dim3(128, 32), dim3(32, 8), 0, stream>>>(Wh, wht);
  fused<<<8256, 256, 0, stream>>>(xs16, wxt, xprj, wht, bias, c0, hbuf, flags, out);
  ys_copy<<<16384, 256, 0, stream>>>(hbuf, out);
}

// Round 9
// 5795.054 us; speedup vs baseline: 1.1241x; 1.1241x over previous
//
#include <hip/hip_runtime.h>

// LSTM: B=64, T=512, D=1024, H=1024.
// v5 = v2 (best measured: fused 5697, total 5930) + gemm producer pacing.
//   v3 (xv-dbuf + ap[32]) and v4 (ys post-pass) both REGRESSED -> scan loop
//   reverted byte-identical to v2. Single change: gemm tiles gate on scan
//   progress (flags[0] >= 2*by - 48, bounded wait) so the ~4 GB of gemm
//   traffic spreads over the whole scan (~0.85 TB/s) instead of saturating
//   L3/HBM (~4 TB/s) during the first ~1.1 ms, which R2 showed costs the
//   scan ~400 us of inflated flag/h round-trips.

typedef _Float16 half8 __attribute__((ext_vector_type(8)));
typedef float floatx4 __attribute__((ext_vector_type(4)));

__device__ __forceinline__ void gll16(const void* g, void* l) {
  __builtin_amdgcn_global_load_lds(
      (const __attribute__((address_space(1))) unsigned int*)g,
      (__attribute__((address_space(3))) unsigned int*)l, 16, 0, 0);
}

__device__ __forceinline__ float sigm(float x) { return 1.f / (1.f + __expf(-x)); }
__device__ __forceinline__ float tanhfast(float x) { return 1.f - 2.f / (__expf(2.f * x) + 1.f); }

// ---------------- prep: convert xs (t-major rows), h0; zero flags/cnt/tot ----------------
__global__ void prep_ew(const float* __restrict__ xs, const float* __restrict__ h0,
                        _Float16* __restrict__ xs16, _Float16* __restrict__ hb0,
                        int* __restrict__ flags) {
  long gid = (long)blockIdx.x * blockDim.x + threadIdx.x;
  if (gid < 4194304) {
    const float4* p = (const float4*)xs + gid * 2;
    float4 u = p[0], w = p[1];
    half8 o;
    o[0] = (_Float16)u.x; o[1] = (_Float16)u.y; o[2] = (_Float16)u.z; o[3] = (_Float16)u.w;
    o[4] = (_Float16)w.x; o[5] = (_Float16)w.y; o[6] = (_Float16)w.z; o[7] = (_Float16)w.w;
    long e = gid * 8;
    long row = e >> 10;               // b*512 + t
    long b = row >> 9, t = row & 511;
    *(half8*)(xs16 + ((t << 6) + b) * 1024 + (e & 1023)) = o;  // row t*64+b
  } else if (gid < 4202496) {
    long j = gid - 4194304;
    const float4* p = (const float4*)h0 + j * 2;
    float4 u = p[0], w = p[1];
    half8 o;
    o[0] = (_Float16)u.x; o[1] = (_Float16)u.y; o[2] = (_Float16)u.z; o[3] = (_Float16)u.w;
    o[4] = (_Float16)w.x; o[5] = (_Float16)w.y; o[6] = (_Float16)w.z; o[7] = (_Float16)w.w;
    *(half8*)(hb0 + j * 8) = o;
  } else if (gid < 4203264) {
    flags[gid - 4202496] = 0;  // flags[0..255], cnt[256..511], tot[512], pad
  }
}

// ---------------- transpose [1024][4096] f32 -> [4096][1024] f16 ----------------
__global__ void transpose_k(const float* __restrict__ in, _Float16* __restrict__ outp) {
  __shared__ float s[32][33];
  int bx = blockIdx.x * 32, by = blockIdx.y * 32;
  int tx = threadIdx.x, ty = threadIdx.y;
#pragma unroll
  for (int k = 0; k < 32; k += 8)
    s[ty + k][tx] = in[(long)(by + ty + k) * 4096 + bx + tx];
  __syncthreads();
#pragma unroll
  for (int k = 0; k < 32; k += 8)
    outp[(long)(bx + ty + k) * 1024 + by + tx] = (_Float16)s[tx][ty + k];
}

// ---------------- fused: gemm1 workers + persistent scan ----------------
// blocks 0..63: scan (wg w owns h-cols [16w,16w+16), wave v owns batches [16v,16v+16))
// blocks 64..8255: gemm tile gid=blk-64, by=gid>>5 (rows 128by.. = t in {2by,2by+1}),
//                  bx=gid&31 (cols 128bx..). Paced by scan progress. Done -> cnt[by]++, tot++.
__global__ __launch_bounds__(256, 1) void fused(const _Float16* __restrict__ xs16,
                                                const _Float16* __restrict__ wxt,
                                                _Float16* __restrict__ xprj,
                                                const _Float16* __restrict__ wht,
                                                const float* __restrict__ bias,
                                                const float* __restrict__ c0,
                                                _Float16* __restrict__ hbuf,
                                                int* __restrict__ flags,
                                                float* __restrict__ out) {
  __shared__ char smem[131072];
  const int tid = threadIdx.x;
  int* const cnt = flags + 256;
  int* const tot = flags + 512;

  if (blockIdx.x >= 64) {
    // ---------------- gemm1 tile ----------------
    _Float16* sA = (_Float16*)smem;
    _Float16* sB = (_Float16*)(smem + 8192);
    const int gid = blockIdx.x - 64;
    const int by = gid >> 5, bx = gid & 31;

    // pace: stay <= 48 steps (24 t-groups) ahead of the scan. Bounded wait
    // (timeout ~220us) -> liveness even under out-of-order dispatch.
    {
      int it = 0;
      for (;;) {
        int tp = __hip_atomic_load(&flags[0], __ATOMIC_RELAXED, __HIP_MEMORY_SCOPE_AGENT);
        if (tp >= 2 * by - 48 || ++it > 256) break;
        __builtin_amdgcn_s_sleep(64);
      }
    }

    const int w = tid >> 6, l = tid & 63, li = l & 15, q = l >> 4;
    const int wr = w >> 1, wc = w & 1;
    const int m0 = by * 128, n0 = bx * 128;
    floatx4 acc[4][4] = {};
    const _Float16* gA0 = xs16 + (long)(m0 + (w * 16 + li)) * 1024 + q * 8;
    const _Float16* gA1 = xs16 + (long)(m0 + ((4 + w) * 16 + li)) * 1024 + q * 8;
    const _Float16* gB0 = wxt + (long)(n0 + (w * 16 + li)) * 1024 + q * 8;
    const _Float16* gB1 = wxt + (long)(n0 + ((4 + w) * 16 + li)) * 1024 + q * 8;
    _Float16* lA0 = sA + (w * 64) * 8;
    _Float16* lA1 = sA + (256 + w * 64) * 8;
    _Float16* lB0 = sB + (w * 64) * 8;
    _Float16* lB1 = sB + (256 + w * 64) * 8;
    for (int k0 = 0; k0 < 1024; k0 += 32) {
      __syncthreads();
      gll16(gA0 + k0, lA0);
      gll16(gA1 + k0, lA1);
      gll16(gB0 + k0, lB0);
      gll16(gB1 + k0, lB1);
      __syncthreads();
      half8 af[4], bf[4];
      const half8* pA = (const half8*)sA;
      const half8* pB = (const half8*)sB;
#pragma unroll
      for (int i = 0; i < 4; i++) af[i] = pA[(wr * 4 + i) * 64 + l];
#pragma unroll
      for (int j = 0; j < 4; j++) bf[j] = pB[(wc * 4 + j) * 64 + l];
#pragma unroll
      for (int i = 0; i < 4; i++)
#pragma unroll
        for (int j = 0; j < 4; j++)
          acc[i][j] = __builtin_amdgcn_mfma_f32_16x16x32_f16(af[i], bf[j], acc[i][j], 0, 0, 0);
    }
#pragma unroll
    for (int i = 0; i < 4; i++) {
#pragma unroll
      for (int r = 0; r < 4; r++) {
        int m = m0 + wr * 64 + i * 16 + q * 4 + r;  // row already t*64+b
#pragma unroll
        for (int j = 0; j < 4; j++) {
          int gn = n0 + wc * 64 + j * 16 + li;
          xprj[(long)m * 4096 + gn] = (_Float16)acc[i][j][r];
        }
      }
    }
    __syncthreads();  // drains all threads' C stores (vmcnt 0 before barrier)
    if (tid == 0) {
      __builtin_amdgcn_fence(__ATOMIC_RELEASE, "agent");
      __hip_atomic_fetch_add(&cnt[by], 1, __ATOMIC_RELAXED, __HIP_MEMORY_SCOPE_AGENT);
      __hip_atomic_fetch_add(tot, 1, __ATOMIC_RELAXED, __HIP_MEMORY_SCOPE_AGENT);
    }
    return;
  }

  // ---------------- scan (byte-identical to v2's measured 5697) ----------------
  _Float16* sW = (_Float16*)smem;  // [g(4)][kk(32)][lane(64)][8] = 128 KB
  const int wgid = blockIdx.x;     // 0..63
  const int v = tid >> 6;          // wave 0..3
  const int l = tid & 63, li = l & 15, q = l >> 4;
  const int ks = wgid * 16;

  // stage Wh^T slice into LDS once: 8192 x 16B chunks
#pragma unroll 4
  for (int i = 0; i < 32; i++) {
    int c = i * 256 + tid;
    int g = c >> 11, kk = (c >> 6) & 31;
    int cli = c & 15, cq = (c >> 4) & 3;
    gll16(wht + (long)((g << 10) + ks + cli) * 1024 + kk * 32 + cq * 8,
          sW + (long)(c - l) * 8);
  }
  float creg[4];
#pragma unroll
  for (int r = 0; r < 4; r++)
    creg[r] = c0[(long)(v * 16 + q * 4 + r) * 1024 + ks + li];
  float bs[4];
#pragma unroll
  for (int g = 0; g < 4; g++) bs[g] = bias[(g << 10) + ks + li];
  __syncthreads();  // sW resident; last barrier in the kernel

  const half8* pW = (const half8*)sW;
  const int fidx = 4 * l + v;  // lane l audits wg l, OWN wave-class only
  int xdone = 0;

  for (int t = 0; t < 512; t++) {
    // gate on xproj readiness for this 2-step group (cheap once gemm is ahead)
    if (!xdone && !(t & 1)) {
      const int nb = t >> 1;
      for (;;) {
        int cr = __hip_atomic_load(&cnt[nb], __ATOMIC_RELAXED, __HIP_MEMORY_SCOPE_AGENT);
        if (cr >= 32) break;
        __builtin_amdgcn_s_sleep(16);
      }
      xdone = (__hip_atomic_load(tot, __ATOMIC_RELAXED, __HIP_MEMORY_SCOPE_AGENT) >= 8192);
      __builtin_amdgcn_fence(__ATOMIC_ACQUIRE, "agent");
    }

    // prefetch this lane's 16 xproj scalars (read-only, hidden behind poll)
    const _Float16* xpt = xprj + (long)t * 262144 + ks + li;
    _Float16 xv[4][4];
#pragma unroll
    for (int g = 0; g < 4; g++)
#pragma unroll
      for (int r = 0; r < 4; r++)
        xv[g][r] = xpt[(long)(v * 16 + q * 4 + r) * 4096 + (g << 10)];

    // one-shot poll of the 64 same-class wave-flags
    for (;;) {
      int f = __hip_atomic_load(&flags[fidx], __ATOMIC_RELAXED, __HIP_MEMORY_SCOPE_AGENT);
      if (__all(f >= t)) break;
      __builtin_amdgcn_s_sleep(1);
    }
    __builtin_amdgcn_fence(__ATOMIC_ACQUIRE, "workgroup");  // no hoisting of h loads

    // K-loop: acc[g] += h_t[16v..16v+16][:] @ Wh[:, g*1024+ks..+16]
    const _Float16* hrow = hbuf + (long)t * 65536 + (long)(v * 16 + li) * 1024 + q * 8;
    floatx4 acc[4] = {};
    half8 ap[8];
#pragma unroll
    for (int p = 0; p < 8; p++) ap[p] = *(const half8*)(hrow + p * 32);
#pragma unroll
    for (int kk = 0; kk < 32; kk++) {
      half8 a = ap[kk & 7];
#pragma unroll
      for (int g = 0; g < 4; g++)
        acc[g] = __builtin_amdgcn_mfma_f32_16x16x32_f16(a, pW[((g * 32 + kk) << 6) + l], acc[g], 0, 0, 0);
      if (kk < 24) ap[kk & 7] = *(const half8*)(hrow + (kk + 8) * 32);
    }

    // epilogue: lane-local gates for (b = 16v+q*4+r, col ks+li)
    _Float16* hnext = hbuf + (long)(t + 1) * 65536;
    float hval[4], cval[4];
#pragma unroll
    for (int r = 0; r < 4; r++) {
      float gi = acc[0][r] + (float)xv[0][r] + bs[0];
      float gf = acc[1][r] + (float)xv[1][r] + bs[1];
      float gg = acc[2][r] + (float)xv[2][r] + bs[2];
      float go = acc[3][r] + (float)xv[3][r] + bs[3];
      float cN = sigm(gf) * creg[r] + sigm(gi) * tanhfast(gg);
      creg[r] = cN;
      cval[r] = cN;
      float hN = sigm(go) * tanhfast(cN);
      hval[r] = hN;
      int b = v * 16 + q * 4 + r;
      unsigned short hu = __builtin_bit_cast(unsigned short, (_Float16)hN);
      __hip_atomic_store((unsigned short*)hnext + (long)b * 1024 + ks + li, hu,
                         __ATOMIC_RELAXED, __HIP_MEMORY_SCOPE_AGENT);
    }
    __builtin_amdgcn_s_waitcnt(0);  // drains ONLY the 4 h stores (rest consumed)
    if (l == 0)
      __hip_atomic_store(&flags[4 * wgid + v], t + 1, __ATOMIC_RELAXED, __HIP_MEMORY_SCOPE_AGENT);

    // slow ys (+ final cT/hT) stores AFTER publishing — off the critical path
#pragma unroll
    for (int r = 0; r < 4; r++) {
      int b = v * 16 + q * 4 + r;
      out[131072 + (long)b * 524288 + (long)t * 1024 + ks + li] = hval[r];
      if (t == 511) {
        out[(long)b * 1024 + ks + li] = cval[r];
        out[65536 + (long)b * 1024 + ks + li] = hval[r];
      }
    }
  }
}

// ---------------- host ----------------
extern "C" void kernel_launch(void* const* d_in, const int* in_sizes, int n_in,
                              void* d_out, int out_size, void* d_ws, size_t ws_size,
                              hipStream_t stream) {
  const float* c0 = (const float*)d_in[0];
  const float* h0 = (const float*)d_in[1];
  const float* xs = (const float*)d_in[2];
  const float* Wx = (const float*)d_in[3];
  const float* Wh = (const float*)d_in[4];
  const float* bias = (const float*)d_in[5];
  float* out = (float*)d_out;

  char* ws = (char*)d_ws;
  size_t off = 0;
  _Float16* xs16 = (_Float16*)(ws + off); off += 67108864;    // 32768x1024 f16 (t-major rows)
  _Float16* wxt  = (_Float16*)(ws + off); off += 8388608;     // 4096x1024 f16
  _Float16* wht  = (_Float16*)(ws + off); off += 8388608;     // 4096x1024 f16
  _Float16* xprj = (_Float16*)(ws + off); off += 268435456;   // 32768x4096 f16
  _Float16* hbuf = (_Float16*)(ws + off); off += 67239936;    // 513x64x1024 f16
  int* flags     = (int*)(ws + off);      off += 4096;        // flags[256], cnt[256], tot
  if (ws_size < off) return;

  prep_ew<<<16419, 256, 0, stream>>>(xs, h0, xs16, hbuf, flags);
  transpose_k<<<dim3(128, 32), dim3(32, 8), 0, stream>>>(Wx, wxt);
  transpose_k<<<dim3(128, 32), dim3(32, 8), 0, stream>>>(Wh, wht);
  fused<<<8256, 256, 0, stream>>>(xs16, wxt, xprj, wht, bias, c0, hbuf, flags, out);
}